// Round 10
// baseline (628.502 us; speedup 1.0000x reference)
//
#include <hip/hip_runtime.h>
#include <hip/hip_bf16.h>
#include <cstdint>

#define N_NODESC  102400
#define N_EDGESC  1638400
#define NUM_GRAPHS 128
#define NPG       800
#define HID       128
#define BN_EPS    1e-5f

#define NFINE 1600           // fine buckets of 64 nodes
#define NCOARSE 25           // coarse buckets of 4096 nodes
#define ROUND 2048           // edges per binning round

typedef short short8 __attribute__((ext_vector_type(8)));
typedef float f32x4  __attribute__((ext_vector_type(4)));
typedef int   intx4  __attribute__((ext_vector_type(4)));
typedef unsigned long long u64;

__device__ __forceinline__ unsigned short f2bf(float f){
    union { __hip_bfloat16 h; unsigned short u; } cv;
    cv.h = __float2bfloat16(f);
    return cv.u;
}
__device__ __forceinline__ float bflo(unsigned int g){ return __uint_as_float(g << 16); }
__device__ __forceinline__ float bfhi(unsigned int g){ return __uint_as_float(g & 0xffff0000u); }
__device__ __forceinline__ float bfu(unsigned short u){ return __uint_as_float(((unsigned int)u) << 16); }

// ----------------- sort pass 0: fine histogram (1600 buckets of 64 dst nodes) -----------------
__global__ __launch_bounds__(256) void k_h1(const int* __restrict__ ei, int* __restrict__ fineCount){
    __shared__ int h[NFINE];
    int t = threadIdx.x;
    for (int i = t; i < NFINE; i += 256) h[i] = 0;
    __syncthreads();
    for (int e = blockIdx.x*256 + t; e < N_EDGESC; e += gridDim.x*256){
        int d = __builtin_nontemporal_load(&ei[N_EDGESC + e]);
        atomicAdd(&h[d >> 6], 1);
    }
    __syncthreads();
    for (int i = t; i < NFINE; i += 256) if (h[i]) atomicAdd(&fineCount[i], h[i]);
}

// ----------------- sort pass 0b: scan 1600 counts -> bases + cursors (1 block) -----------------
__global__ __launch_bounds__(256) void k_scanF(const int* __restrict__ fineCount, int* __restrict__ fineBase,
                                               int* __restrict__ fineCursor, int* __restrict__ coarseCursor){
    __shared__ int part[256];
    __shared__ int shb[NFINE];
    int t = threadIdx.x;
    int loc[7]; int s = 0;
    #pragma unroll
    for (int j = 0; j < 7; j++){
        int idx = t*7 + j;
        int v = (idx < NFINE) ? fineCount[idx] : 0;
        loc[j] = s; s += v;
    }
    part[t] = s;
    __syncthreads();
    if (t == 0){
        int run = 0;
        for (int i = 0; i < 256; i++){ int v = part[i]; part[i] = run; run += v; }
    }
    __syncthreads();
    #pragma unroll
    for (int j = 0; j < 7; j++){
        int idx = t*7 + j;
        if (idx < NFINE){
            int b = part[t] + loc[j];
            shb[idx] = b;
            fineBase[idx]   = b;
            fineCursor[idx] = b;
        }
    }
    __syncthreads();
    if (t < NCOARSE) coarseCursor[t] = shb[t*64];
}

// ----------------- sort pass 1: bin edges into 25 coarse buckets (LDS round compaction) -----------------
__global__ __launch_bounds__(256) void k_binA(const int* __restrict__ ei, int* __restrict__ coarseCursor,
                                              u64* __restrict__ coarseBuf){
    __shared__ int cnt[NCOARSE], gpos[NCOARSE], baseS[NCOARSE+1];
    __shared__ u64 stage[ROUND];
    __shared__ short bkt[ROUND];
    int t = threadIdx.x;
    int chunk = blockIdx.x * ROUND;
    if (t < NCOARSE) cnt[t] = 0;
    __syncthreads();
    u64 ed[8]; int b[8], rk[8];
    #pragma unroll
    for (int j = 0; j < 8; j++){
        int e = chunk + t + j*256;
        unsigned int s = (unsigned int)__builtin_nontemporal_load(&ei[e]);
        unsigned int d = (unsigned int)__builtin_nontemporal_load(&ei[N_EDGESC + e]);
        ed[j] = ((u64)d << 32) | (u64)s;
        b[j] = (int)(d >> 12);
        rk[j] = atomicAdd(&cnt[b[j]], 1);
    }
    __syncthreads();
    if (t == 0){
        int s = 0;
        for (int i = 0; i < NCOARSE; i++){ baseS[i] = s; s += cnt[i]; }
        baseS[NCOARSE] = s;
    }
    __syncthreads();
    if (t < NCOARSE && cnt[t] > 0) gpos[t] = atomicAdd(&coarseCursor[t], cnt[t]);
    __syncthreads();
    #pragma unroll
    for (int j = 0; j < 8; j++){
        int p = baseS[b[j]] + rk[j];
        stage[p] = ed[j];
        bkt[p] = (short)b[j];
    }
    __syncthreads();
    #pragma unroll
    for (int j = 0; j < 8; j++){
        int p = t + j*256;
        int bb = bkt[p];
        coarseBuf[gpos[bb] + (p - baseS[bb])] = stage[p];
    }
}

// ----------------- sort pass 2: coarse -> 64 fine sub-buckets each -----------------
__global__ __launch_bounds__(256) void k_binB(const u64* __restrict__ coarseBuf, const int* __restrict__ fineBase,
                                              int* __restrict__ fineCursor, u64* __restrict__ fineBuf){
    int c   = blockIdx.x >> 5;
    int sub = blockIdx.x & 31;
    int segB = fineBase[c*64];
    int segE = (c == NCOARSE-1) ? N_EDGESC : fineBase[(c+1)*64];
    __shared__ int cnt[64], gpos[64], baseS[65];
    __shared__ u64 stage[ROUND];
    __shared__ short bkt[ROUND];
    int t = threadIdx.x;
    for (int r = sub; ; r += 32){
        int base = segB + r*ROUND;
        if (base >= segE) break;
        int m = segE - base; if (m > ROUND) m = ROUND;
        if (t < 64) cnt[t] = 0;
        __syncthreads();
        u64 ed[8]; int b[8], rk[8], val[8];
        #pragma unroll
        for (int j = 0; j < 8; j++){
            int i = t + j*256;
            val[j] = (i < m);
            if (val[j]){
                ed[j] = __builtin_nontemporal_load(&coarseBuf[base + i]);
                b[j] = (int)((ed[j] >> 38) & 63);
                rk[j] = atomicAdd(&cnt[b[j]], 1);
            }
        }
        __syncthreads();
        if (t == 0){
            int s = 0;
            for (int i = 0; i < 64; i++){ baseS[i] = s; s += cnt[i]; }
            baseS[64] = s;
        }
        __syncthreads();
        if (t < 64 && cnt[t] > 0) gpos[t] = atomicAdd(&fineCursor[c*64 + t], cnt[t]);
        __syncthreads();
        #pragma unroll
        for (int j = 0; j < 8; j++){
            if (val[j]){
                int p = baseS[b[j]] + rk[j];
                stage[p] = ed[j];
                bkt[p] = (short)b[j];
            }
        }
        __syncthreads();
        int total = baseS[64];
        #pragma unroll
        for (int j = 0; j < 8; j++){
            int p = t + j*256;
            if (p < total){
                int bb = bkt[p];
                fineBuf[gpos[bb] + (p - baseS[bb])] = stage[p];
            }
        }
        __syncthreads();
    }
}

// ----------------- sort pass 3: per fine bucket (64 nodes) build CSR + dinv, scatter srcS -----------------
__global__ __launch_bounds__(256) void k_binC(const u64* __restrict__ fineBuf, const int* __restrict__ fineBase,
                                              const int* __restrict__ fineCount, int* __restrict__ row_ptr,
                                              float* __restrict__ dinv, int* __restrict__ srcS){
    int f = blockIdx.x, t = threadIdx.x;
    int gB = fineBase[f];
    int cntE = fineCount[f];
    __shared__ int deg[64], excl[64], cur[64];
    if (t < 64){ deg[t] = 0; cur[t] = 0; }
    __syncthreads();
    for (int i = t; i < cntE; i += 256){
        int lo = (int)((fineBuf[gB + i] >> 32) & 63);
        atomicAdd(&deg[lo], 1);
    }
    __syncthreads();
    if (t == 0){
        int s = 0;
        for (int i = 0; i < 64; i++){ excl[i] = s; s += deg[i]; }
    }
    __syncthreads();
    if (t < 64){
        row_ptr[f*64 + t] = gB + excl[t];
        dinv[f*64 + t] = rsqrtf((float)(deg[t] + 1));
    }
    if (f == 0 && t == 0) row_ptr[N_NODESC] = N_EDGESC;
    for (int i = t; i < cntE; i += 256){
        u64 ed = fineBuf[gB + i];
        int lo = (int)((ed >> 32) & 63);
        int pos = gB + excl[lo] + atomicAdd(&cur[lo], 1);
        srcS[pos] = (int)(unsigned int)(ed & 0xffffffffu);
    }
}

// ----------------- W0^T in bf16 + zero-init of fineCount/stats/biasv -----------------
__global__ __launch_bounds__(256) void k_prepw0(const float* __restrict__ W, unsigned short* __restrict__ Wt,
                                                int* __restrict__ fineCount, float* __restrict__ stats,
                                                float* __restrict__ biasv){
    int idx = blockIdx.x*256 + threadIdx.x;
    int n = idx & 127, k = idx >> 7;
    Wt[n*128 + k] = f2bf(W[k*128 + n]);
    if (idx < NFINE) fineCount[idx] = 0;
    else if (idx < NFINE + 768) stats[idx - NFINE] = 0.f;
    else if (idx < NFINE + 768 + 128) biasv[idx - NFINE - 768] = 0.f;
}

// ----------------- MFMA bf16 GEMM: Hd = bf16(dinv[row] * (X @ W + biasv)) -----------------
template<int F32IN>
__global__ __launch_bounds__(256) void k_gemm_mfma(const void* __restrict__ Xin,
        const unsigned short* __restrict__ Wt, const float* __restrict__ biasv,
        const float* __restrict__ dinv, unsigned short* __restrict__ H){
    int l   = threadIdx.x & 63;
    int wid = threadIdx.x >> 6;
    int R   = blockIdx.x*64 + wid*16;
    int r0  = l & 15;
    int kg  = l >> 4;
    short8 a[4];
    if (F32IN){
        const float* X = (const float*)Xin;
        #pragma unroll
        for (int kk = 0; kk < 4; kk++){
            const float* p = X + (size_t)(R + r0)*HID + kk*32 + kg*8;
            float4 u = *(const float4*)p;
            float4 v = *(const float4*)(p + 4);
            short8 tt;
            tt[0]=(short)f2bf(u.x); tt[1]=(short)f2bf(u.y); tt[2]=(short)f2bf(u.z); tt[3]=(short)f2bf(u.w);
            tt[4]=(short)f2bf(v.x); tt[5]=(short)f2bf(v.y); tt[6]=(short)f2bf(v.z); tt[7]=(short)f2bf(v.w);
            a[kk] = tt;
        }
    } else {
        const unsigned short* X = (const unsigned short*)Xin;
        #pragma unroll
        for (int kk = 0; kk < 4; kk++)
            a[kk] = *(const short8*)(X + (size_t)(R + r0)*HID + kk*32 + kg*8);
    }
    f32x4 acc[8];
    #pragma unroll
    for (int i = 0; i < 8; i++) acc[i] = (f32x4)(0.f);
    #pragma unroll
    for (int kk = 0; kk < 4; kk++){
        #pragma unroll
        for (int nf = 0; nf < 8; nf++){
            short8 b = *(const short8*)(Wt + (size_t)(nf*16 + r0)*HID + kk*32 + kg*8);
            acc[nf] = __builtin_amdgcn_mfma_f32_16x16x32_bf16(a[kk], b, acc[nf], 0, 0, 0);
        }
    }
    float bv[8];
    #pragma unroll
    for (int nf = 0; nf < 8; nf++) bv[nf] = biasv[nf*16 + r0];
    #pragma unroll
    for (int r = 0; r < 4; r++){
        int row = R + kg*4 + r;
        float di = dinv[row];
        #pragma unroll
        for (int nf = 0; nf < 8; nf++)
            H[(size_t)row*HID + nf*16 + r0] = f2bf(di * (acc[nf][r] + bv[nf]));
    }
}

// --------- dual-node aggregation + relu + fused BN stats; nt metadata loads, h rows keep L2 ---------
// OUT[n] = relu( dinv[n] * (sum_e Hd[src_e] + Hd[n]) + b )
__global__ __launch_bounds__(256) void k_agg(const unsigned int* __restrict__ Hb, const int* __restrict__ row_ptr,
                                             const int* __restrict__ srcS, const float* __restrict__ dinv,
                                             const float* __restrict__ bconv,
                                             unsigned int* __restrict__ OUT, float* __restrict__ sum,
                                             float* __restrict__ sumsq){
    int lane = threadIdx.x & 63;
    int w    = threadIdx.x >> 6;
    int wave = blockIdx.x*4 + w;
    int nw   = gridDim.x*4;
    float2 bc = ((const float2*)bconv)[lane];
    float sx0 = 0.f, sx1 = 0.f, sq0 = 0.f, sq1 = 0.f;
    const int NPAIR = N_NODESC/2;
    for (int pb = wave; pb < NPAIR; pb += nw){
        int nA = 2*pb, nB = 2*pb + 1;
        int eA  = __builtin_nontemporal_load(&row_ptr[nA]);
        int e1A = __builtin_nontemporal_load(&row_ptr[nA+1]);
        int e1B = __builtin_nontemporal_load(&row_ptr[nB+1]);
        int eB  = e1A;
        unsigned int gsA = Hb[(size_t)nA*64 + lane];
        unsigned int gsB = Hb[(size_t)nB*64 + lane];
        float axA = bflo(gsA), ayA = bfhi(gsA);
        float axB = bflo(gsB), ayB = bfhi(gsB);
        while (eA + 4 <= e1A && eB + 4 <= e1B){
            intx4 sa = __builtin_nontemporal_load((const intx4*)(srcS + eA));
            intx4 sb = __builtin_nontemporal_load((const intx4*)(srcS + eB));
            unsigned int g0 = Hb[(size_t)sa[0]*64 + lane];
            unsigned int g1 = Hb[(size_t)sa[1]*64 + lane];
            unsigned int g2 = Hb[(size_t)sa[2]*64 + lane];
            unsigned int g3 = Hb[(size_t)sa[3]*64 + lane];
            unsigned int h0 = Hb[(size_t)sb[0]*64 + lane];
            unsigned int h1 = Hb[(size_t)sb[1]*64 + lane];
            unsigned int h2 = Hb[(size_t)sb[2]*64 + lane];
            unsigned int h3 = Hb[(size_t)sb[3]*64 + lane];
            axA += bflo(g0); ayA += bfhi(g0);
            axA += bflo(g1); ayA += bfhi(g1);
            axA += bflo(g2); ayA += bfhi(g2);
            axA += bflo(g3); ayA += bfhi(g3);
            axB += bflo(h0); ayB += bfhi(h0);
            axB += bflo(h1); ayB += bfhi(h1);
            axB += bflo(h2); ayB += bfhi(h2);
            axB += bflo(h3); ayB += bfhi(h3);
            eA += 4; eB += 4;
        }
        for (; eA + 4 <= e1A; eA += 4){
            intx4 sa = __builtin_nontemporal_load((const intx4*)(srcS + eA));
            unsigned int g0 = Hb[(size_t)sa[0]*64 + lane];
            unsigned int g1 = Hb[(size_t)sa[1]*64 + lane];
            unsigned int g2 = Hb[(size_t)sa[2]*64 + lane];
            unsigned int g3 = Hb[(size_t)sa[3]*64 + lane];
            axA += bflo(g0); ayA += bfhi(g0);
            axA += bflo(g1); ayA += bfhi(g1);
            axA += bflo(g2); ayA += bfhi(g2);
            axA += bflo(g3); ayA += bfhi(g3);
        }
        for (; eB + 4 <= e1B; eB += 4){
            intx4 sb = __builtin_nontemporal_load((const intx4*)(srcS + eB));
            unsigned int h0 = Hb[(size_t)sb[0]*64 + lane];
            unsigned int h1 = Hb[(size_t)sb[1]*64 + lane];
            unsigned int h2 = Hb[(size_t)sb[2]*64 + lane];
            unsigned int h3 = Hb[(size_t)sb[3]*64 + lane];
            axB += bflo(h0); ayB += bfhi(h0);
            axB += bflo(h1); ayB += bfhi(h1);
            axB += bflo(h2); ayB += bfhi(h2);
            axB += bflo(h3); ayB += bfhi(h3);
        }
        while (eA < e1A || eB < e1B){
            unsigned int g = 0, h = 0;
            int doA = (eA < e1A), doB = (eB < e1B);
            if (doA) g = Hb[(size_t)__builtin_nontemporal_load(&srcS[eA])*64 + lane];
            if (doB) h = Hb[(size_t)__builtin_nontemporal_load(&srcS[eB])*64 + lane];
            if (doA){ axA += bflo(g); ayA += bfhi(g); eA++; }
            if (doB){ axB += bflo(h); ayB += bfhi(h); eB++; }
        }
        float dA = dinv[nA], dB = dinv[nB];
        axA = fmaxf(fmaf(axA, dA, bc.x), 0.f);
        ayA = fmaxf(fmaf(ayA, dA, bc.y), 0.f);
        axB = fmaxf(fmaf(axB, dB, bc.x), 0.f);
        ayB = fmaxf(fmaf(ayB, dB, bc.y), 0.f);
        unsigned int oA = ((unsigned int)f2bf(ayA) << 16) | (unsigned int)f2bf(axA);
        unsigned int oB = ((unsigned int)f2bf(ayB) << 16) | (unsigned int)f2bf(axB);
        __builtin_nontemporal_store(oA, &OUT[(size_t)nA*64 + lane]);
        __builtin_nontemporal_store(oB, &OUT[(size_t)nB*64 + lane]);
        sx0 += axA + axB; sq0 += axA*axA + axB*axB;
        sx1 += ayA + ayB; sq1 += ayA*ayA + ayB*ayB;
    }
    __shared__ float shs[4][128];
    __shared__ float shq[4][128];
    shs[w][2*lane]   = sx0; shs[w][2*lane+1] = sx1;
    shq[w][2*lane]   = sq0; shq[w][2*lane+1] = sq1;
    __syncthreads();
    int t = threadIdx.x;
    if (t < 128){
        atomicAdd(&sum[t],   shs[0][t] + shs[1][t] + shs[2][t] + shs[3][t]);
        atomicAdd(&sumsq[t], shq[0][t] + shq[1][t] + shq[2][t] + shq[3][t]);
    }
}

// ----------------- BN finalize: A, B, folded bias + W fold (1 block) -----------------
__global__ __launch_bounds__(128) void k_finalize(const float* __restrict__ sum, const float* __restrict__ sumsq,
                                                  const float* __restrict__ gamma, const float* __restrict__ beta,
                                                  const float* __restrict__ Wnext, float* __restrict__ A,
                                                  float* __restrict__ B, unsigned short* __restrict__ WpT,
                                                  float* __restrict__ biasv, int hasNext){
    __shared__ float Ash[128], Bsh[128];
    int c = threadIdx.x;
    const float invN = 1.0f / (float)N_NODESC;
    float mu  = sum[c] * invN;
    float var = sumsq[c] * invN - mu*mu;
    float is  = rsqrtf(var + BN_EPS);
    float a = is * gamma[c];
    float b = beta[c] - mu * a;
    A[c] = a; B[c] = b; Ash[c] = a; Bsh[c] = b;
    __syncthreads();
    if (hasNext){
        float bv = 0.f;
        for (int k = 0; k < 128; k++){
            float w = Wnext[k*128 + c];
            WpT[c*128 + k] = f2bf(Ash[k] * w);
            bv = fmaf(Bsh[k], w, bv);
        }
        biasv[c] = bv;
    }
}

// ----------------- fused readout: pool (max/mean/first w/ BN) + MLP + log_softmax, 1 block/graph -----------------
__global__ __launch_bounds__(512) void k_poolmlp(const unsigned short* __restrict__ X, const float* __restrict__ A,
                                                 const float* __restrict__ B, const float* __restrict__ W1,
                                                 const float* __restrict__ b1, const float* __restrict__ W2,
                                                 const float* __restrict__ b2, float* __restrict__ out){
    __shared__ float shm[4][128];
    __shared__ float shsm[4][128];
    __shared__ float row[384];
    __shared__ float t1[384];
    __shared__ float r0[512], r1[512];
    int t = threadIdx.x, gr = blockIdx.x;
    int c = t & 127, sl = t >> 7;    // 4 slices x 200 nodes
    float a = A[c], b = B[c];
    const unsigned short* base = X + ((size_t)gr*NPG + sl*200)*HID;
    float mx = -1e30f, sm = 0.f;
    for (int i = 0; i < 200; i++){
        float v = fmaf(bfu(base[(size_t)i*HID + c]), a, b);
        mx = fmaxf(mx, v); sm += v;
    }
    shm[sl][c] = mx; shsm[sl][c] = sm;
    if (sl == 0) row[256 + c] = fmaf(bfu(base[c]), a, b);   // first node of graph
    __syncthreads();
    if (t < 128){
        float m = fmaxf(fmaxf(shm[0][t], shm[1][t]), fmaxf(shm[2][t], shm[3][t]));
        float s = shsm[0][t] + shsm[1][t] + shsm[2][t] + shsm[3][t];
        row[t]       = m;
        row[128 + t] = s * (1.0f/(float)NPG);
    }
    __syncthreads();
    if (t < 384){
        float acc = b1[t];
        for (int k = 0; k < 384; k++) acc = fmaf(row[k], W1[(size_t)k*384 + t], acc);
        t1[t] = acc;
    }
    __syncthreads();
    float p0 = 0.f, p1 = 0.f;
    if (t < 384){ float v = t1[t]; p0 = v*W2[t*2]; p1 = v*W2[t*2+1]; }
    r0[t] = p0; r1[t] = p1; __syncthreads();
    for (int off = 256; off > 0; off >>= 1){
        if (t < off){ r0[t] += r0[t+off]; r1[t] += r1[t+off]; }
        __syncthreads();
    }
    if (t == 0){
        float o0 = r0[0] + b2[0], o1 = r1[0] + b2[1];
        float m = fmaxf(o0, o1);
        float lse = m + logf(expf(o0 - m) + expf(o1 - m));
        out[gr*2 + 0] = o0 - lse;
        out[gr*2 + 1] = o1 - lse;
    }
}

extern "C" void kernel_launch(void* const* d_in, const int* in_sizes, int n_in,
                              void* d_out, int out_size, void* d_ws, size_t ws_size,
                              hipStream_t stream){
    const float* x     = (const float*)d_in[0];
    const int*   ei    = (const int*)d_in[1];
    const float* Wconv = (const float*)d_in[3];
    const float* bconv = (const float*)d_in[4];
    const float* gamma = (const float*)d_in[5];
    const float* beta  = (const float*)d_in[6];
    const float* W1    = (const float*)d_in[7];
    const float* b1    = (const float*)d_in[8];
    const float* W2    = (const float*)d_in[9];
    const float* b2    = (const float*)d_in[10];
    float* out = (float*)d_out;

    char* p = (char*)d_ws;
    size_t off = 0;
    auto alloc = [&](size_t bytes)->char* {
        char* r = p + off; off += (bytes + 255) & ~(size_t)255; return r;
    };
    unsigned short* buf1 = (unsigned short*)alloc((size_t)N_NODESC*HID*2);  // Hd = bf16(dinv*(x@W+b))
    unsigned short* buf2 = (unsigned short*)alloc((size_t)N_NODESC*HID*2);  // post-agg relu'd bf16
    u64*  coarseBuf  = (u64*)  alloc((size_t)N_EDGESC*8);
    u64*  fineBuf    = (u64*)  alloc((size_t)N_EDGESC*8);
    int*   srcS      = (int*)  alloc((size_t)N_EDGESC*4);
    int*   row_ptr   = (int*)  alloc((size_t)(N_NODESC+1)*4);
    float* dinv      = (float*)alloc((size_t)N_NODESC*4);
    int*   fineCount = (int*)  alloc(NFINE*4);
    int*   fineBase  = (int*)  alloc(NFINE*4);
    int*   fineCursor= (int*)  alloc(NFINE*4);
    int*   coarseCursor=(int*) alloc(NCOARSE*4);
    float* stats   = (float*)alloc(3*2*128*4);
    float* AB      = (float*)alloc(3*2*128*4);
    unsigned short* Wt0 = (unsigned short*)alloc(128*128*2);
    unsigned short* WpT = (unsigned short*)alloc(128*128*2);
    float* biasv   = (float*)alloc(512);
    (void)ws_size; (void)in_sizes; (void)n_in; (void)out_size;

    // prepw0 first: converts W0^T and zero-inits fineCount/stats/biasv (no memsets needed)
    k_prepw0<<<64, 256, 0, stream>>>(Wconv, Wt0, fineCount, stats, biasv);

    // CSR build via 2-level LDS-staged counting sort
    k_h1   <<<256, 256, 0, stream>>>(ei, fineCount);
    k_scanF<<<1,   256, 0, stream>>>(fineCount, fineBase, fineCursor, coarseCursor);
    k_binA <<<N_EDGESC/ROUND, 256, 0, stream>>>(ei, coarseCursor, coarseBuf);
    k_binB <<<NCOARSE*32, 256, 0, stream>>>(coarseBuf, fineBase, fineCursor, fineBuf);
    k_binC <<<NFINE, 256, 0, stream>>>(fineBuf, fineBase, fineCount, row_ptr, dinv, srcS);

    for (int l = 0; l < 3; l++){
        if (l == 0)
            k_gemm_mfma<1><<<N_NODESC/64, 256, 0, stream>>>((const void*)x, Wt0, biasv, dinv, buf1);
        else
            k_gemm_mfma<0><<<N_NODESC/64, 256, 0, stream>>>((const void*)buf2, WpT, biasv, dinv, buf1);
        k_agg<<<4096, 256, 0, stream>>>((const unsigned int*)buf1, row_ptr, srcS, dinv,
                                        bconv + l*HID, (unsigned int*)buf2,
                                        stats + l*256, stats + l*256 + 128);
        k_finalize<<<1, 128, 0, stream>>>(stats + l*256, stats + l*256 + 128,
                                          gamma + l*HID, beta + l*HID,
                                          Wconv + (size_t)(l+1 < 3 ? l+1 : 0)*HID*HID,
                                          AB + l*256, AB + l*256 + 128,
                                          WpT, biasv, (l < 2) ? 1 : 0);
    }
    k_poolmlp<<<NUM_GRAPHS, 512, 0, stream>>>(buf2, AB + 2*256, AB + 2*256 + 128,
                                              W1, b1, W2, b2, out);
}

// Round 11
// 527.940 us; speedup vs baseline: 1.1905x; 1.1905x over previous
//
#include <hip/hip_runtime.h>
#include <hip/hip_bf16.h>
#include <cstdint>

#define N_NODESC  102400
#define N_EDGESC  1638400
#define NUM_GRAPHS 128
#define NPG       800
#define HID       128
#define BN_EPS    1e-5f

#define NFINE 1600           // fine buckets of 64 nodes
#define NCOARSE 25           // coarse buckets of 4096 nodes
#define ROUND 2048           // edges per binning round

typedef short short8 __attribute__((ext_vector_type(8)));
typedef float f32x4  __attribute__((ext_vector_type(4)));
typedef unsigned long long u64;

__device__ __forceinline__ unsigned short f2bf(float f){
    union { __hip_bfloat16 h; unsigned short u; } cv;
    cv.h = __float2bfloat16(f);
    return cv.u;
}
__device__ __forceinline__ float bflo(unsigned int g){ return __uint_as_float(g << 16); }
__device__ __forceinline__ float bfhi(unsigned int g){ return __uint_as_float(g & 0xffff0000u); }
__device__ __forceinline__ float bfu(unsigned short u){ return __uint_as_float(((unsigned int)u) << 16); }

// ----------------- sort pass 0: fine histogram (1600 buckets of 64 dst nodes) -----------------
__global__ __launch_bounds__(256) void k_h1(const int* __restrict__ ei, int* __restrict__ fineCount){
    __shared__ int h[NFINE];
    int t = threadIdx.x;
    for (int i = t; i < NFINE; i += 256) h[i] = 0;
    __syncthreads();
    for (int e = blockIdx.x*256 + t; e < N_EDGESC; e += gridDim.x*256){
        int d = __builtin_nontemporal_load(&ei[N_EDGESC + e]);
        atomicAdd(&h[d >> 6], 1);
    }
    __syncthreads();
    for (int i = t; i < NFINE; i += 256) if (h[i]) atomicAdd(&fineCount[i], h[i]);
}

// ----------------- sort pass 0b: scan 1600 counts -> bases + cursors (1 block) -----------------
__global__ __launch_bounds__(256) void k_scanF(const int* __restrict__ fineCount, int* __restrict__ fineBase,
                                               int* __restrict__ fineCursor, int* __restrict__ coarseCursor){
    __shared__ int part[256];
    __shared__ int shb[NFINE];
    int t = threadIdx.x;
    int loc[7]; int s = 0;
    #pragma unroll
    for (int j = 0; j < 7; j++){
        int idx = t*7 + j;
        int v = (idx < NFINE) ? fineCount[idx] : 0;
        loc[j] = s; s += v;
    }
    part[t] = s;
    __syncthreads();
    if (t == 0){
        int run = 0;
        for (int i = 0; i < 256; i++){ int v = part[i]; part[i] = run; run += v; }
    }
    __syncthreads();
    #pragma unroll
    for (int j = 0; j < 7; j++){
        int idx = t*7 + j;
        if (idx < NFINE){
            int b = part[t] + loc[j];
            shb[idx] = b;
            fineBase[idx]   = b;
            fineCursor[idx] = b;
        }
    }
    __syncthreads();
    if (t < NCOARSE) coarseCursor[t] = shb[t*64];
}

// ----------------- sort pass 1: bin edges into 25 coarse buckets (LDS round compaction) -----------------
__global__ __launch_bounds__(256) void k_binA(const int* __restrict__ ei, int* __restrict__ coarseCursor,
                                              u64* __restrict__ coarseBuf){
    __shared__ int cnt[NCOARSE], gpos[NCOARSE], baseS[NCOARSE+1];
    __shared__ u64 stage[ROUND];
    __shared__ short bkt[ROUND];
    int t = threadIdx.x;
    int chunk = blockIdx.x * ROUND;
    if (t < NCOARSE) cnt[t] = 0;
    __syncthreads();
    u64 ed[8]; int b[8], rk[8];
    #pragma unroll
    for (int j = 0; j < 8; j++){
        int e = chunk + t + j*256;
        unsigned int s = (unsigned int)__builtin_nontemporal_load(&ei[e]);
        unsigned int d = (unsigned int)__builtin_nontemporal_load(&ei[N_EDGESC + e]);
        ed[j] = ((u64)d << 32) | (u64)s;
        b[j] = (int)(d >> 12);
        rk[j] = atomicAdd(&cnt[b[j]], 1);
    }
    __syncthreads();
    if (t == 0){
        int s = 0;
        for (int i = 0; i < NCOARSE; i++){ baseS[i] = s; s += cnt[i]; }
        baseS[NCOARSE] = s;
    }
    __syncthreads();
    if (t < NCOARSE && cnt[t] > 0) gpos[t] = atomicAdd(&coarseCursor[t], cnt[t]);
    __syncthreads();
    #pragma unroll
    for (int j = 0; j < 8; j++){
        int p = baseS[b[j]] + rk[j];
        stage[p] = ed[j];
        bkt[p] = (short)b[j];
    }
    __syncthreads();
    #pragma unroll
    for (int j = 0; j < 8; j++){
        int p = t + j*256;
        int bb = bkt[p];
        coarseBuf[gpos[bb] + (p - baseS[bb])] = stage[p];
    }
}

// ----------------- sort pass 2: coarse -> 64 fine sub-buckets each -----------------
__global__ __launch_bounds__(256) void k_binB(const u64* __restrict__ coarseBuf, const int* __restrict__ fineBase,
                                              int* __restrict__ fineCursor, u64* __restrict__ fineBuf){
    int c   = blockIdx.x >> 5;
    int sub = blockIdx.x & 31;
    int segB = fineBase[c*64];
    int segE = (c == NCOARSE-1) ? N_EDGESC : fineBase[(c+1)*64];
    __shared__ int cnt[64], gpos[64], baseS[65];
    __shared__ u64 stage[ROUND];
    __shared__ short bkt[ROUND];
    int t = threadIdx.x;
    for (int r = sub; ; r += 32){
        int base = segB + r*ROUND;
        if (base >= segE) break;
        int m = segE - base; if (m > ROUND) m = ROUND;
        if (t < 64) cnt[t] = 0;
        __syncthreads();
        u64 ed[8]; int b[8], rk[8], val[8];
        #pragma unroll
        for (int j = 0; j < 8; j++){
            int i = t + j*256;
            val[j] = (i < m);
            if (val[j]){
                ed[j] = __builtin_nontemporal_load(&coarseBuf[base + i]);
                b[j] = (int)((ed[j] >> 38) & 63);
                rk[j] = atomicAdd(&cnt[b[j]], 1);
            }
        }
        __syncthreads();
        if (t == 0){
            int s = 0;
            for (int i = 0; i < 64; i++){ baseS[i] = s; s += cnt[i]; }
            baseS[64] = s;
        }
        __syncthreads();
        if (t < 64 && cnt[t] > 0) gpos[t] = atomicAdd(&fineCursor[c*64 + t], cnt[t]);
        __syncthreads();
        #pragma unroll
        for (int j = 0; j < 8; j++){
            if (val[j]){
                int p = baseS[b[j]] + rk[j];
                stage[p] = ed[j];
                bkt[p] = (short)b[j];
            }
        }
        __syncthreads();
        int total = baseS[64];
        #pragma unroll
        for (int j = 0; j < 8; j++){
            int p = t + j*256;
            if (p < total){
                int bb = bkt[p];
                fineBuf[gpos[bb] + (p - baseS[bb])] = stage[p];
            }
        }
        __syncthreads();
    }
}

// ----------------- sort pass 3: per fine bucket (64 nodes) build CSR + dinv, scatter srcS -----------------
__global__ __launch_bounds__(256) void k_binC(const u64* __restrict__ fineBuf, const int* __restrict__ fineBase,
                                              const int* __restrict__ fineCount, int* __restrict__ row_ptr,
                                              float* __restrict__ dinv, int* __restrict__ srcS){
    int f = blockIdx.x, t = threadIdx.x;
    int gB = fineBase[f];
    int cntE = fineCount[f];
    __shared__ int deg[64], excl[64], cur[64];
    if (t < 64){ deg[t] = 0; cur[t] = 0; }
    __syncthreads();
    for (int i = t; i < cntE; i += 256){
        int lo = (int)((fineBuf[gB + i] >> 32) & 63);
        atomicAdd(&deg[lo], 1);
    }
    __syncthreads();
    if (t == 0){
        int s = 0;
        for (int i = 0; i < 64; i++){ excl[i] = s; s += deg[i]; }
    }
    __syncthreads();
    if (t < 64){
        row_ptr[f*64 + t] = gB + excl[t];
        dinv[f*64 + t] = rsqrtf((float)(deg[t] + 1));
    }
    if (f == 0 && t == 0) row_ptr[N_NODESC] = N_EDGESC;
    for (int i = t; i < cntE; i += 256){
        u64 ed = fineBuf[gB + i];
        int lo = (int)((ed >> 32) & 63);
        int pos = gB + excl[lo] + atomicAdd(&cur[lo], 1);
        srcS[pos] = (int)(unsigned int)(ed & 0xffffffffu);
    }
}

// ----------------- W0^T in bf16 + zero-init of fineCount/stats/biasv -----------------
__global__ __launch_bounds__(256) void k_prepw0(const float* __restrict__ W, unsigned short* __restrict__ Wt,
                                                int* __restrict__ fineCount, float* __restrict__ stats,
                                                float* __restrict__ biasv){
    int idx = blockIdx.x*256 + threadIdx.x;
    int n = idx & 127, k = idx >> 7;
    Wt[n*128 + k] = f2bf(W[k*128 + n]);
    if (idx < NFINE) fineCount[idx] = 0;
    else if (idx < NFINE + 768) stats[idx - NFINE] = 0.f;
    else if (idx < NFINE + 768 + 128) biasv[idx - NFINE - 768] = 0.f;
}

// ----------------- MFMA bf16 GEMM: Hd = bf16(dinv[row] * (X @ W + biasv)) -----------------
template<int F32IN>
__global__ __launch_bounds__(256) void k_gemm_mfma(const void* __restrict__ Xin,
        const unsigned short* __restrict__ Wt, const float* __restrict__ biasv,
        const float* __restrict__ dinv, unsigned short* __restrict__ H){
    int l   = threadIdx.x & 63;
    int wid = threadIdx.x >> 6;
    int R   = blockIdx.x*64 + wid*16;
    int r0  = l & 15;
    int kg  = l >> 4;
    short8 a[4];
    if (F32IN){
        const float* X = (const float*)Xin;
        #pragma unroll
        for (int kk = 0; kk < 4; kk++){
            const float* p = X + (size_t)(R + r0)*HID + kk*32 + kg*8;
            float4 u = *(const float4*)p;
            float4 v = *(const float4*)(p + 4);
            short8 tt;
            tt[0]=(short)f2bf(u.x); tt[1]=(short)f2bf(u.y); tt[2]=(short)f2bf(u.z); tt[3]=(short)f2bf(u.w);
            tt[4]=(short)f2bf(v.x); tt[5]=(short)f2bf(v.y); tt[6]=(short)f2bf(v.z); tt[7]=(short)f2bf(v.w);
            a[kk] = tt;
        }
    } else {
        const unsigned short* X = (const unsigned short*)Xin;
        #pragma unroll
        for (int kk = 0; kk < 4; kk++)
            a[kk] = *(const short8*)(X + (size_t)(R + r0)*HID + kk*32 + kg*8);
    }
    f32x4 acc[8];
    #pragma unroll
    for (int i = 0; i < 8; i++) acc[i] = (f32x4)(0.f);
    #pragma unroll
    for (int kk = 0; kk < 4; kk++){
        #pragma unroll
        for (int nf = 0; nf < 8; nf++){
            short8 b = *(const short8*)(Wt + (size_t)(nf*16 + r0)*HID + kk*32 + kg*8);
            acc[nf] = __builtin_amdgcn_mfma_f32_16x16x32_bf16(a[kk], b, acc[nf], 0, 0, 0);
        }
    }
    float bv[8];
    #pragma unroll
    for (int nf = 0; nf < 8; nf++) bv[nf] = biasv[nf*16 + r0];
    #pragma unroll
    for (int r = 0; r < 4; r++){
        int row = R + kg*4 + r;
        float di = dinv[row];
        #pragma unroll
        for (int nf = 0; nf < 8; nf++)
            H[(size_t)row*HID + nf*16 + r0] = f2bf(di * (acc[nf][r] + bv[nf]));
    }
}

// --------- dual-node aggregation + relu + fused BN stats; two independent gather chains/wave ---------
// OUT[n] = relu( dinv[n] * (sum_e Hd[src_e] + Hd[n]) + b )
__global__ __launch_bounds__(256) void k_agg(const unsigned int* __restrict__ Hb, const int* __restrict__ row_ptr,
                                             const int* __restrict__ srcS, const float* __restrict__ dinv,
                                             const float* __restrict__ bconv,
                                             unsigned int* __restrict__ OUT, float* __restrict__ sum,
                                             float* __restrict__ sumsq){
    int lane = threadIdx.x & 63;
    int w    = threadIdx.x >> 6;
    int wave = blockIdx.x*4 + w;
    int nw   = gridDim.x*4;
    float2 bc = ((const float2*)bconv)[lane];
    float sx0 = 0.f, sx1 = 0.f, sq0 = 0.f, sq1 = 0.f;
    const int NPAIR = N_NODESC/2;
    for (int pb = wave; pb < NPAIR; pb += nw){
        int nA = 2*pb, nB = 2*pb + 1;
        int eA  = row_ptr[nA], e1A = row_ptr[nA+1], e1B = row_ptr[nB+1];
        int eB  = e1A;
        unsigned int gsA = Hb[(size_t)nA*64 + lane];
        unsigned int gsB = Hb[(size_t)nB*64 + lane];
        float axA = bflo(gsA), ayA = bfhi(gsA);
        float axB = bflo(gsB), ayB = bfhi(gsB);
        while (eA + 4 <= e1A && eB + 4 <= e1B){
            int4 sa = *(const int4*)(srcS + eA);
            int4 sb = *(const int4*)(srcS + eB);
            unsigned int g0 = Hb[(size_t)sa.x*64 + lane];
            unsigned int g1 = Hb[(size_t)sa.y*64 + lane];
            unsigned int g2 = Hb[(size_t)sa.z*64 + lane];
            unsigned int g3 = Hb[(size_t)sa.w*64 + lane];
            unsigned int h0 = Hb[(size_t)sb.x*64 + lane];
            unsigned int h1 = Hb[(size_t)sb.y*64 + lane];
            unsigned int h2 = Hb[(size_t)sb.z*64 + lane];
            unsigned int h3 = Hb[(size_t)sb.w*64 + lane];
            axA += bflo(g0); ayA += bfhi(g0);
            axA += bflo(g1); ayA += bfhi(g1);
            axA += bflo(g2); ayA += bfhi(g2);
            axA += bflo(g3); ayA += bfhi(g3);
            axB += bflo(h0); ayB += bfhi(h0);
            axB += bflo(h1); ayB += bfhi(h1);
            axB += bflo(h2); ayB += bfhi(h2);
            axB += bflo(h3); ayB += bfhi(h3);
            eA += 4; eB += 4;
        }
        for (; eA + 4 <= e1A; eA += 4){
            int4 sa = *(const int4*)(srcS + eA);
            unsigned int g0 = Hb[(size_t)sa.x*64 + lane];
            unsigned int g1 = Hb[(size_t)sa.y*64 + lane];
            unsigned int g2 = Hb[(size_t)sa.z*64 + lane];
            unsigned int g3 = Hb[(size_t)sa.w*64 + lane];
            axA += bflo(g0); ayA += bfhi(g0);
            axA += bflo(g1); ayA += bfhi(g1);
            axA += bflo(g2); ayA += bfhi(g2);
            axA += bflo(g3); ayA += bfhi(g3);
        }
        for (; eB + 4 <= e1B; eB += 4){
            int4 sb = *(const int4*)(srcS + eB);
            unsigned int h0 = Hb[(size_t)sb.x*64 + lane];
            unsigned int h1 = Hb[(size_t)sb.y*64 + lane];
            unsigned int h2 = Hb[(size_t)sb.z*64 + lane];
            unsigned int h3 = Hb[(size_t)sb.w*64 + lane];
            axB += bflo(h0); ayB += bfhi(h0);
            axB += bflo(h1); ayB += bfhi(h1);
            axB += bflo(h2); ayB += bfhi(h2);
            axB += bflo(h3); ayB += bfhi(h3);
        }
        while (eA < e1A || eB < e1B){
            unsigned int g = 0, h = 0;
            int doA = (eA < e1A), doB = (eB < e1B);
            if (doA) g = Hb[(size_t)srcS[eA]*64 + lane];
            if (doB) h = Hb[(size_t)srcS[eB]*64 + lane];
            if (doA){ axA += bflo(g); ayA += bfhi(g); eA++; }
            if (doB){ axB += bflo(h); ayB += bfhi(h); eB++; }
        }
        float dA = dinv[nA], dB = dinv[nB];
        axA = fmaxf(fmaf(axA, dA, bc.x), 0.f);
        ayA = fmaxf(fmaf(ayA, dA, bc.y), 0.f);
        axB = fmaxf(fmaf(axB, dB, bc.x), 0.f);
        ayB = fmaxf(fmaf(ayB, dB, bc.y), 0.f);
        unsigned int oA = ((unsigned int)f2bf(ayA) << 16) | (unsigned int)f2bf(axA);
        unsigned int oB = ((unsigned int)f2bf(ayB) << 16) | (unsigned int)f2bf(axB);
        __builtin_nontemporal_store(oA, &OUT[(size_t)nA*64 + lane]);
        __builtin_nontemporal_store(oB, &OUT[(size_t)nB*64 + lane]);
        sx0 += axA + axB; sq0 += axA*axA + axB*axB;
        sx1 += ayA + ayB; sq1 += ayA*ayA + ayB*ayB;
    }
    __shared__ float shs[4][128];
    __shared__ float shq[4][128];
    shs[w][2*lane]   = sx0; shs[w][2*lane+1] = sx1;
    shq[w][2*lane]   = sq0; shq[w][2*lane+1] = sq1;
    __syncthreads();
    int t = threadIdx.x;
    if (t < 128){
        atomicAdd(&sum[t],   shs[0][t] + shs[1][t] + shs[2][t] + shs[3][t]);
        atomicAdd(&sumsq[t], shq[0][t] + shq[1][t] + shq[2][t] + shq[3][t]);
    }
}

// ----------------- BN finalize: A, B, folded bias + W fold (1 block) -----------------
__global__ __launch_bounds__(128) void k_finalize(const float* __restrict__ sum, const float* __restrict__ sumsq,
                                                  const float* __restrict__ gamma, const float* __restrict__ beta,
                                                  const float* __restrict__ Wnext, float* __restrict__ A,
                                                  float* __restrict__ B, unsigned short* __restrict__ WpT,
                                                  float* __restrict__ biasv, int hasNext){
    __shared__ float Ash[128], Bsh[128];
    int c = threadIdx.x;
    const float invN = 1.0f / (float)N_NODESC;
    float mu  = sum[c] * invN;
    float var = sumsq[c] * invN - mu*mu;
    float is  = rsqrtf(var + BN_EPS);
    float a = is * gamma[c];
    float b = beta[c] - mu * a;
    A[c] = a; B[c] = b; Ash[c] = a; Bsh[c] = b;
    __syncthreads();
    if (hasNext){
        float bv = 0.f;
        for (int k = 0; k < 128; k++){
            float w = Wnext[k*128 + c];
            WpT[c*128 + k] = f2bf(Ash[k] * w);
            bv = fmaf(Bsh[k], w, bv);
        }
        biasv[c] = bv;
    }
}

// ----------------- fused readout: pool (max/mean/first w/ BN) + MLP + log_softmax, 1 block/graph -----------------
__global__ __launch_bounds__(512) void k_poolmlp(const unsigned short* __restrict__ X, const float* __restrict__ A,
                                                 const float* __restrict__ B, const float* __restrict__ W1,
                                                 const float* __restrict__ b1, const float* __restrict__ W2,
                                                 const float* __restrict__ b2, float* __restrict__ out){
    __shared__ float shm[4][128];
    __shared__ float shsm[4][128];
    __shared__ float row[384];
    __shared__ float t1[384];
    __shared__ float r0[512], r1[512];
    int t = threadIdx.x, gr = blockIdx.x;
    int c = t & 127, sl = t >> 7;    // 4 slices x 200 nodes
    float a = A[c], b = B[c];
    const unsigned short* base = X + ((size_t)gr*NPG + sl*200)*HID;
    float mx = -1e30f, sm = 0.f;
    for (int i = 0; i < 200; i++){
        float v = fmaf(bfu(base[(size_t)i*HID + c]), a, b);
        mx = fmaxf(mx, v); sm += v;
    }
    shm[sl][c] = mx; shsm[sl][c] = sm;
    if (sl == 0) row[256 + c] = fmaf(bfu(base[c]), a, b);   // first node of graph
    __syncthreads();
    if (t < 128){
        float m = fmaxf(fmaxf(shm[0][t], shm[1][t]), fmaxf(shm[2][t], shm[3][t]));
        float s = shsm[0][t] + shsm[1][t] + shsm[2][t] + shsm[3][t];
        row[t]       = m;
        row[128 + t] = s * (1.0f/(float)NPG);
    }
    __syncthreads();
    if (t < 384){
        float acc = b1[t];
        for (int k = 0; k < 384; k++) acc = fmaf(row[k], W1[(size_t)k*384 + t], acc);
        t1[t] = acc;
    }
    __syncthreads();
    float p0 = 0.f, p1 = 0.f;
    if (t < 384){ float v = t1[t]; p0 = v*W2[t*2]; p1 = v*W2[t*2+1]; }
    r0[t] = p0; r1[t] = p1; __syncthreads();
    for (int off = 256; off > 0; off >>= 1){
        if (t < off){ r0[t] += r0[t+off]; r1[t] += r1[t+off]; }
        __syncthreads();
    }
    if (t == 0){
        float o0 = r0[0] + b2[0], o1 = r1[0] + b2[1];
        float m = fmaxf(o0, o1);
        float lse = m + logf(expf(o0 - m) + expf(o1 - m));
        out[gr*2 + 0] = o0 - lse;
        out[gr*2 + 1] = o1 - lse;
    }
}

extern "C" void kernel_launch(void* const* d_in, const int* in_sizes, int n_in,
                              void* d_out, int out_size, void* d_ws, size_t ws_size,
                              hipStream_t stream){
    const float* x     = (const float*)d_in[0];
    const int*   ei    = (const int*)d_in[1];
    const float* Wconv = (const float*)d_in[3];
    const float* bconv = (const float*)d_in[4];
    const float* gamma = (const float*)d_in[5];
    const float* beta  = (const float*)d_in[6];
    const float* W1    = (const float*)d_in[7];
    const float* b1    = (const float*)d_in[8];
    const float* W2    = (const float*)d_in[9];
    const float* b2    = (const float*)d_in[10];
    float* out = (float*)d_out;

    char* p = (char*)d_ws;
    size_t off = 0;
    auto alloc = [&](size_t bytes)->char* {
        char* r = p + off; off += (bytes + 255) & ~(size_t)255; return r;
    };
    unsigned short* buf1 = (unsigned short*)alloc((size_t)N_NODESC*HID*2);  // Hd = bf16(dinv*(x@W+b))
    unsigned short* buf2 = (unsigned short*)alloc((size_t)N_NODESC*HID*2);  // post-agg relu'd bf16
    u64*  coarseBuf  = (u64*)  alloc((size_t)N_EDGESC*8);
    u64*  fineBuf    = (u64*)  alloc((size_t)N_EDGESC*8);
    int*   srcS      = (int*)  alloc((size_t)N_EDGESC*4);
    int*   row_ptr   = (int*)  alloc((size_t)(N_NODESC+1)*4);
    float* dinv      = (float*)alloc((size_t)N_NODESC*4);
    int*   fineCount = (int*)  alloc(NFINE*4);
    int*   fineBase  = (int*)  alloc(NFINE*4);
    int*   fineCursor= (int*)  alloc(NFINE*4);
    int*   coarseCursor=(int*) alloc(NCOARSE*4);
    float* stats   = (float*)alloc(3*2*128*4);
    float* AB      = (float*)alloc(3*2*128*4);
    unsigned short* Wt0 = (unsigned short*)alloc(128*128*2);
    unsigned short* WpT = (unsigned short*)alloc(128*128*2);
    float* biasv   = (float*)alloc(512);
    (void)ws_size; (void)in_sizes; (void)n_in; (void)out_size;

    // prepw0 first: converts W0^T and zero-inits fineCount/stats/biasv (no memsets needed)
    k_prepw0<<<64, 256, 0, stream>>>(Wconv, Wt0, fineCount, stats, biasv);

    // CSR build via 2-level LDS-staged counting sort
    k_h1   <<<256, 256, 0, stream>>>(ei, fineCount);
    k_scanF<<<1,   256, 0, stream>>>(fineCount, fineBase, fineCursor, coarseCursor);
    k_binA <<<N_EDGESC/ROUND, 256, 0, stream>>>(ei, coarseCursor, coarseBuf);
    k_binB <<<NCOARSE*32, 256, 0, stream>>>(coarseBuf, fineBase, fineCursor, fineBuf);
    k_binC <<<NFINE, 256, 0, stream>>>(fineBuf, fineBase, fineCount, row_ptr, dinv, srcS);

    for (int l = 0; l < 3; l++){
        if (l == 0)
            k_gemm_mfma<1><<<N_NODESC/64, 256, 0, stream>>>((const void*)x, Wt0, biasv, dinv, buf1);
        else
            k_gemm_mfma<0><<<N_NODESC/64, 256, 0, stream>>>((const void*)buf2, WpT, biasv, dinv, buf1);
        k_agg<<<2048, 256, 0, stream>>>((const unsigned int*)buf1, row_ptr, srcS, dinv,
                                        bconv + l*HID, (unsigned int*)buf2,
                                        stats + l*256, stats + l*256 + 128);
        k_finalize<<<1, 128, 0, stream>>>(stats + l*256, stats + l*256 + 128,
                                          gamma + l*HID, beta + l*HID,
                                          Wconv + (size_t)(l+1 < 3 ? l+1 : 0)*HID*HID,
                                          AB + l*256, AB + l*256 + 128,
                                          WpT, biasv, (l < 2) ? 1 : 0);
    }
    k_poolmlp<<<NUM_GRAPHS, 512, 0, stream>>>(buf2, AB + 2*256, AB + 2*256 + 128,
                                              W1, b1, W2, b2, out);
}